// Round 6
// baseline (166.768 us; speedup 1.0000x reference)
//
#include <hip/hip_runtime.h>

#define IN_D 112
#define OUT_D 111
#define MDIM 16
#define DC 4            // d-outputs per thread
#define NSLAB (DC + 1)  // slabs d0 .. d0+DC (R1=2 window)

// Lane layout: lane = 4*ci + q. ci = local column (0..15), q = channel quad.
// Wave g covers output columns g*15 .. g*15+14.
//
// Rounds 1-5 unified post-mortem: VGPR_Count pinned at 64 in EVERY variant,
// so at most ~1-2 of the 10 slab loads can be in flight per wave (load dests
// need VGPRs). Wave latency math: 52.6us x (2.8 resident / 24.3 waves per
// SIMD) ~ 14.4K cycles ~ 14 VMEM ops x ~950cyc serialized round trips, with
// only ~1200 cyc VALU hidden under them (VALUBusy 22%). Latency-bound by the
// register file, not BW (40%), not VALU, not DS.
//
// Round-6 fix: global_load_lds DMA staging. Loads consume ZERO VGPRs, so all
// 10 x 1KB transfers per wave are concurrently in flight; one __syncthreads
// (vmcnt drain) covers them all. Compute reads back via linear ds_read_b128
// (the exact layout the DMA writes: wave-uniform base + lane*16B).
__device__ __forceinline__ float4 f4add(float4 a, float4 b) {
    return make_float4(a.x + b.x, a.y + b.y, a.z + b.z, a.w + b.w);
}
__device__ __forceinline__ float4 shfl_down4(float4 v) {
    return make_float4(__shfl_down(v.x, 4, 64), __shfl_down(v.y, 4, 64),
                       __shfl_down(v.z, 4, 64), __shfl_down(v.w, 4, 64));
}

// DPP quad_perm broadcast of lane j within each quad: ctrl = j*0x55.
template <int CTRL>
__device__ __forceinline__ float dppf(float v) {
    return __int_as_float(
        __builtin_amdgcn_mov_dpp(__float_as_int(v), CTRL, 0xF, 0xF, false));
}
template <int CTRL>
__device__ __forceinline__ float4 dpp4(float4 v) {
    return make_float4(dppf<CTRL>(v.x), dppf<CTRL>(v.y),
                       dppf<CTRL>(v.z), dppf<CTRL>(v.w));
}
__device__ __forceinline__ float dot4(float4 a, float4 b) {
    return a.x * b.x + a.y * b.y + a.z * b.z + a.w * b.w;
}

// Async global->LDS DMA: 16B per lane. Global addr is per-lane; LDS dest is
// wave-uniform base, HW adds lane*16.
__device__ __forceinline__ void dma16(const float* gp, float* lp) {
    __builtin_amdgcn_global_load_lds(
        (const __attribute__((address_space(1))) void*)gp,
        (__attribute__((address_space(3))) void*)lp, 16, 0, 0);
}

__global__ __launch_bounds__(256)
void spatial_dual_desc_kernel(const float* __restrict__ x,
                              const float* __restrict__ Mg,
                              float* __restrict__ out) {
    const int lane = threadIdx.x & 63;
    const int wid  = threadIdx.x >> 6;          // 0..3
    const int g    = blockIdx.x * 4 + wid;      // wave slot 0..7
    const int ci   = lane >> 2;                 // 0..15
    const int q    = lane & 3;                  // 0..3
    const int col  = g * 15 + ci;               // candidate output column
    const int c    = (col < IN_D) ? col : (IN_D - 1);
    const int h    = blockIdx.y;
    const int d0   = blockIdx.z * DC;

    __shared__ float Ms[MDIM * MDIM];
    __shared__ __align__(16) float stage[4][NSLAB][2][256];  // 40 KB

    Ms[threadIdx.x] = Mg[threadIdx.x];

    const size_t row_stride  = (size_t)IN_D * MDIM;          // h step (floats)
    const size_t slab_stride = (size_t)IN_D * row_stride;    // d step (floats)
    const float* bp = x + ((size_t)h * IN_D + c) * MDIM + 4 * q;

    // Issue all 10 DMA transfers back-to-back: 10 KB in flight per wave.
#pragma unroll
    for (int j = 0; j < NSLAB; ++j) {
        int dj = d0 + j;
        if (dj > IN_D - 1) dj = IN_D - 1;
        const float* p = bp + (size_t)dj * slab_stride;
        dma16(p,              &stage[wid][j][0][0]);
        dma16(p + row_stride, &stage[wid][j][1][0]);
    }

    __syncthreads();   // drains vmcnt (all DMAs done) + publishes Ms

    // M as natural rows: Mrow[i][j] = cols 4j..4j+3 of row (4q+i).
    // Broadcast reads (4 distinct addresses across the wave) -> conflict-free;
    // if the allocator remats these per k-step it's cheap LDS broadcast.
    float4 Mrow[4][4];
#pragma unroll
    for (int i = 0; i < 4; ++i)
#pragma unroll
        for (int j = 0; j < 4; ++j)
            Mrow[i][j] = *(const float4*)(&Ms[(4 * q + i) * MDIM + 4 * j]);

#define SLAB(j, r) (*(const float4*)(&stage[wid][j][r][lane * 4]))

    float4 rs_prev = f4add(SLAB(0, 0), SLAB(0, 1));   // row-pair sum, slab d0

#pragma unroll
    for (int k = 0; k < DC; ++k) {
        const int dcur = d0 + k;
        float4 rs_new = f4add(SLAB(k + 1, 0), SLAB(k + 1, 1));

        // d-pair, then w-pair (neighbor column = lane+4).
        float4 s4 = f4add(rs_prev, rs_new);
        float4 w4 = f4add(s4, shfl_down4(s4));

        // Broadcast each quad's float4 to all 4 lanes of the quad: every lane
        // holds the full 16-component window vector in natural order.
        float4 u0 = dpp4<0x00>(w4);
        float4 u1 = dpp4<0x55>(w4);
        float4 u2 = dpp4<0xAA>(w4);
        float4 u3 = dpp4<0xFF>(w4);

        float o[4];
#pragma unroll
        for (int i = 0; i < 4; ++i) {
            float acc = dot4(u0, Mrow[i][0]) + dot4(u1, Mrow[i][1])
                      + dot4(u2, Mrow[i][2]) + dot4(u3, Mrow[i][3]);
            o[i] = acc * 0.125f;
        }

        if (ci < 15 && col < OUT_D && dcur < OUT_D) {
            *(float4*)(out + (((size_t)dcur * OUT_D + h) * OUT_D + col) * MDIM + 4 * q)
                = make_float4(o[0], o[1], o[2], o[3]);
        }
        rs_prev = rs_new;
    }
#undef SLAB
}

extern "C" void kernel_launch(void* const* d_in, const int* in_sizes, int n_in,
                              void* d_out, int out_size, void* d_ws, size_t ws_size,
                              hipStream_t stream) {
    const float* x = (const float*)d_in[0];   // (112,112,112,16) fp32
    const float* M = (const float*)d_in[1];   // (16,16) fp32
    float* out = (float*)d_out;               // (111^3, 16) fp32

    dim3 block(256, 1, 1);
    dim3 grid(2, OUT_D, (OUT_D + DC - 1) / DC);   // 2 x 111 x 28
    spatial_dual_desc_kernel<<<grid, block, 0, stream>>>(x, M, out);
}